// Round 7
// baseline (1107.050 us; speedup 1.0000x reference)
//
#include <hip/hip_runtime.h>

// ---------------- problem constants ----------------
#define E_EDGES 64800
#define NC      842
#define NB      8          // b*t = 2*4
#define FIN     78
#define E_LAT   5894
#define NROWS_NODE (NB*NC)   // 6736
#define EPB      48          // edges per tile (MF=3), 64800 = 1350*48 exact
#define NT_TILES 1350
#define N_ITERS  (NT_TILES*NB)   // 10800 tile-iterations
#define EDGE_GRID 256            // persistent, 1 block/CU
#define NODE_B   421
#define TAIL_B   192             // tail blocks fused into node dispatch

// output layout (flat float32)
#define OUT_IDX_OFF   1724416
#define OUT_IDX_N     11788
#define OUT_ATTR_OFF  1736204

// workspace layout (bytes)
#define AGG_OFF    0
#define CNT_OFF    6897664
#define CUR_OFF    6901032
#define SSRC_OFF   6904400
#define SDST_OFF   7163600
#define SATTR_OFF  7293200
#define WPACK_OFF  7811600

// packed-weight element offsets (bf16 elements)
#define WOFF_E0 0
#define WOFF_E1 40960
#define WOFF_E2 106496
#define WOFF_N0 172032
#define WOFF_N1 262144
#define WOFF_N2 327680
#define WOFF_R0 393216
#define WOFF_R1 401408
#define WOFF_R2 466944

// LDS strides (bf16 elems): dword stride ≡ 3 or 5 (mod 8) keeps b128 A-frag
// reads ≤2-way bank-aliased (free).
#define SH   262
#define SA_N 362

typedef __bf16 bf16x8 __attribute__((ext_vector_type(8)));
typedef float  f32x4  __attribute__((ext_vector_type(4)));

__device__ __forceinline__ unsigned short f2bf(float f) {   // RNE (pack_weights only)
    unsigned u = __builtin_bit_cast(unsigned, f);
    return (unsigned short)((u + 0x7fffu + ((u >> 16) & 1u)) >> 16);
}
// RTZ pack of two floats into two bf16 in one v_perm_b32
__device__ __forceinline__ unsigned packRTZ(float lo, float hi) {
    return __builtin_amdgcn_perm(__builtin_bit_cast(unsigned, hi),
                                 __builtin_bit_cast(unsigned, lo), 0x07060302u);
}

template<int MF, int NF>
__device__ __forceinline__ void zero_acc(f32x4 (&acc)[MF][NF]) {
#pragma unroll
    for (int mf = 0; mf < MF; ++mf)
#pragma unroll
        for (int nf = 0; nf < NF; ++nf)
            acc[mf][nf] = (f32x4){0.f, 0.f, 0.f, 0.f};
}

// ---- K-loop with B entirely in registers (edge kernel, 8 waves x 32 cols) ----
// Zero global traffic in the loop: only LDS A-reads (same addr across waves ->
// broadcast) + MFMA.  All wr indices compile-time after unroll.
template<int MF, int NKS>
__device__ __forceinline__ void run_layer_reg(const unsigned short* lA,
                                              const bf16x8 (&wr)[NKS][2],
                                              int m15, int q, f32x4 (&acc)[MF][2]) {
#pragma unroll
    for (int kk = 0; kk < NKS; ++kk) {
        bf16x8 a[MF];
#pragma unroll
        for (int mf = 0; mf < MF; ++mf)
            a[mf] = *(const bf16x8*)(lA + (mf * 16 + m15) * SH + kk * 32 + q * 8);
#pragma unroll
        for (int nf = 0; nf < 2; ++nf)
#pragma unroll
            for (int mf = 0; mf < MF; ++mf)
                acc[mf][nf] = __builtin_amdgcn_mfma_f32_16x16x32_bf16(a[mf], wr[kk][nf], acc[mf][nf], 0, 0, 0);
    }
}

// C += A_lds * Wpacked with B-fragment register prefetch (node/tail kernels).
template<int MF, int NKS>
__device__ __forceinline__ void run_layer(const unsigned short* lA, int strideA,
                                          const unsigned short* Wp, int nfg0,
                                          int m15, int q, f32x4 (&acc)[MF][4]) {
    const unsigned short* wp0 = Wp + (size_t)nfg0 * 512 + (threadIdx.x & 63) * 8;
    bf16x8 bcur[4], bnxt[4];
#pragma unroll
    for (int nf = 0; nf < 4; ++nf) bcur[nf] = *(const bf16x8*)(wp0 + nf * 512);
#pragma unroll
    for (int kk = 0; kk < NKS; ++kk) {
        if (kk + 1 < NKS) {
#pragma unroll
            for (int nf = 0; nf < 4; ++nf)
                bnxt[nf] = *(const bf16x8*)(wp0 + (size_t)(kk + 1) * 16 * 512 + nf * 512);
        }
        bf16x8 a[MF];
#pragma unroll
        for (int mf = 0; mf < MF; ++mf)
            a[mf] = *(const bf16x8*)(lA + (mf * 16 + m15) * strideA + kk * 32 + q * 8);
#pragma unroll
        for (int nf = 0; nf < 4; ++nf)
#pragma unroll
            for (int mf = 0; mf < MF; ++mf)
                acc[mf][nf] = __builtin_amdgcn_mfma_f32_16x16x32_bf16(a[mf], bcur[nf], acc[mf][nf], 0, 0, 0);
#pragma unroll
        for (int nf = 0; nf < 4; ++nf) bcur[nf] = bnxt[nf];
    }
}

// S[(rowbase+row)*stride+col] = bf16_rtz(leaky(acc + bias[col]))
template<int MF, int NF>
__device__ __forceinline__ void epi_act(unsigned short* Sb, int stride, const f32x4 (&acc)[MF][NF],
                                        const float* bias, int colbase, int rowbase,
                                        int m15, int q) {
#pragma unroll
    for (int nf = 0; nf < NF; ++nf) {
        int col = colbase + nf * 16 + m15;
        float bv = bias[col];
#pragma unroll
        for (int mf = 0; mf < MF; ++mf)
#pragma unroll
            for (int r4 = 0; r4 < 4; ++r4) {
                int row = rowbase + mf * 16 + q * 4 + r4;
                float y = acc[mf][nf][r4] + bv;
                y = fmaxf(y, 0.01f * y);
                Sb[row * stride + col] = (unsigned short)(__builtin_bit_cast(unsigned, y) >> 16);
            }
    }
}

// ---------------- weight packing ----------------
__global__ void pack_weights(const float* s0, const float* s1, const float* s2,
                             const float* s3, const float* s4, const float* s5,
                             const float* s6, const float* s7, const float* s8,
                             unsigned short* wp) {
    const int ksA[9]  = {5, 8, 8, 11, 8, 8, 1, 8, 8};
    const int kaA[9]  = {158, 256, 256, 334, 256, 256, 2, 256, 256};
    const int offA[9] = {WOFF_E0, WOFF_E1, WOFF_E2, WOFF_N0, WOFF_N1, WOFF_N2,
                         WOFF_R0, WOFF_R1, WOFF_R2};
    const float* srcs[9] = {s0, s1, s2, s3, s4, s5, s6, s7, s8};
    int rem = blockIdx.x;
    int l = 0;
    while (rem >= ksA[l] * 16) { rem -= ksA[l] * 16; ++l; }
    int kk = rem >> 4, nf = rem & 15;
    int lane = threadIdx.x >> 3, j = threadIdx.x & 7;
    int k = kk * 32 + (lane >> 4) * 8 + j;
    int n = nf * 16 + (lane & 15);
    float v = (k < kaA[l]) ? srcs[l][k * 256 + n] : 0.f;
    wp[(size_t)offA[l] + (size_t)(kk * 16 + nf) * 512 + lane * 8 + j] = f2bf(v);
}

// ---------------- counting sort of edges by dst (+ gather sorted meta) ----------------
__global__ void hist_kernel(const int* __restrict__ dstA, int* __restrict__ cnt) {
    int e = blockIdx.x * 256 + threadIdx.x;
    if (e < E_EDGES) atomicAdd(&cnt[dstA[e]], 1);
}
__global__ void scan_kernel(const int* __restrict__ cnt, int* __restrict__ cursor) {
    __shared__ int s[1024];
    int t = threadIdx.x;
    s[t] = (t < NC) ? cnt[t] : 0;
    __syncthreads();
    for (int d = 1; d < 1024; d <<= 1) {
        int v = (t >= d) ? s[t - d] : 0;
        __syncthreads();
        s[t] += v;
        __syncthreads();
    }
    if (t < NC) cursor[t] = (t == 0) ? 0 : s[t - 1];
}
__global__ void scatter_kernel(const int* __restrict__ srcA, const int* __restrict__ dstA,
                               const float* __restrict__ eattr, int* __restrict__ cursor,
                               int* __restrict__ ssrc, short* __restrict__ sdst,
                               float2* __restrict__ sattr) {
    int e = blockIdx.x * 256 + threadIdx.x;
    if (e < E_EDGES) {
        int d = dstA[e];
        int p = atomicAdd(&cursor[d], 1);
        ssrc[p] = srcA[e];
        sdst[p] = (short)d;
        sattr[p] = ((const float2*)eattr)[e];
    }
}

// ------- persistent edge MLP: 512 thr (8 waves x 32 cols), weights in regs ----
// 1 block/CU (launch_bounds 512,1 -> 256-VGPR cap; R5 failed at the (512,2)
// 128-reg cap).  Each wave preloads its 32-col slice of all 3 layers ONCE
// (21 K-steps x 2 nf x 4 VGPR = 168 regs), then the block loops over 10800
// 48-edge x 1-batch tiles.  Steady-state K-loop: LDS A-reads + MFMA only.
__global__ __launch_bounds__(512, 1) void edge_mlp_kernel(
    const float* __restrict__ x, const float* __restrict__ h3,
    const float* __restrict__ eb0, const float* __restrict__ eb1, const float* __restrict__ eb2,
    const unsigned short* __restrict__ wpack, const int* __restrict__ ssrc,
    const short* __restrict__ sdst, const float2* __restrict__ sattr,
    float* __restrict__ agg) {
    __shared__ __align__(16) unsigned short S[EPB * SH];   // A(160) then H(256) overlay
    __shared__ short dstl[EPB];
    __shared__ unsigned char starts[EPB + 4];
    __shared__ int nseg;

    const int tid = threadIdx.x, lane = tid & 63, w = tid >> 6;   // w in 0..7
    const int m15 = lane & 15, q = lane >> 4;

    // ---- preload this wave's 32-col weight slice into registers (once) ----
    const unsigned short* wb = wpack + (size_t)(w * 2) * 512 + lane * 8;
    bf16x8 wE0[5][2], wE1[8][2], wE2[8][2];
#pragma unroll
    for (int kk = 0; kk < 5; ++kk)
#pragma unroll
        for (int nf = 0; nf < 2; ++nf)
            wE0[kk][nf] = *(const bf16x8*)(wb + WOFF_E0 + (kk * 16 + nf) * 512);
#pragma unroll
    for (int kk = 0; kk < 8; ++kk)
#pragma unroll
        for (int nf = 0; nf < 2; ++nf) {
            wE1[kk][nf] = *(const bf16x8*)(wb + WOFF_E1 + (kk * 16 + nf) * 512);
            wE2[kk][nf] = *(const bf16x8*)(wb + WOFF_E2 + (kk * 16 + nf) * 512);
        }
    float bnf[2];
#pragma unroll
    for (int nf = 0; nf < 2; ++nf) bnf[nf] = eb2[w * 32 + nf * 16 + m15];

    const int rr = tid >> 3, j = tid & 7;   // staging: 8 threads/row, rows 0..47

    for (int it = blockIdx.x; it < N_ITERS; it += gridDim.x) {
        const int t = it % NT_TILES, b = it / NT_TILES;
        const int base = t * EPB;
        __syncthreads();   // prev iter's flush reads dstl/starts; S reused

        if (tid < EPB) dstl[tid] = sdst[base + tid];
        __syncthreads();   // dstl ready for staging + scan

        if (tid == 0) {    // serial segment scan (48 rows)
            int ns = 0; short prev = -2;
            for (int r = 0; r < EPB; ++r) {
                short d = dstl[r];
                if (d != prev) { starts[ns++] = (unsigned char)r; prev = d; }
            }
            starts[ns] = EPB;
            nseg = ns;
        }

        // stage layer-0 input [x(78)|h3(78)|attr(2)|pad(2)] at stride SH, RTZ pack
        if (rr < EPB) {
            const int eg = base + rr;
            const float* xr = x + ((size_t)b * E_EDGES + ssrc[eg]) * FIN;
            const float* hr = h3 + (int)dstl[rr] * FIN;
            unsigned short* Sr = S + rr * SH;
#pragma unroll
            for (int tt = 0; tt < 5; ++tt) {
                int p = j + 8 * tt;
                if (p < 39) {
                    float2 f = *(const float2*)(xr + 2 * p);
                    float2 g = *(const float2*)(hr + 2 * p);
                    *(unsigned*)(Sr + 2 * p) = packRTZ(f.x, f.y);
                    *(unsigned*)(Sr + 78 + 2 * p) = packRTZ(g.x, g.y);
                } else if (p == 39) {
                    float2 a2 = sattr[eg];
                    *(unsigned*)(Sr + 156) = packRTZ(a2.x, a2.y);
                    *(unsigned*)(Sr + 158) = 0;
                }
            }
        }
        __syncthreads();

        f32x4 acc[3][2];
        zero_acc(acc);
        run_layer_reg<3, 5>(S, wE0, m15, q, acc);   // K=160
        __syncthreads();
        epi_act(S, SH, acc, eb0, w * 32, 0, m15, q);
        __syncthreads();

        zero_acc(acc);
        run_layer_reg<3, 8>(S, wE1, m15, q, acc);   // K=256
        __syncthreads();
        epi_act(S, SH, acc, eb1, w * 32, 0, m15, q);
        __syncthreads();

        zero_acc(acc);
        run_layer_reg<3, 8>(S, wE2, m15, q, acc);   // K=256

        // segment reduce + predicated atomic flush (cols w*32 + nf*16 + m15)
        const int ns = nseg;
#pragma unroll
        for (int nf = 0; nf < 2; ++nf) {
            const float bv = bnf[nf];
            for (int s = 0; s < ns; ++s) {
                const int lo = starts[s], hi = starts[s + 1];
                float tv = 0.f;
#pragma unroll
                for (int mf = 0; mf < 3; ++mf)
#pragma unroll
                    for (int r4 = 0; r4 < 4; ++r4) {
                        int row = mf * 16 + q * 4 + r4;
                        tv += (row >= lo && row < hi) ? acc[mf][nf][r4] : 0.f;
                    }
                tv += __shfl_xor(tv, 16, 64);
                tv += __shfl_xor(tv, 32, 64);
                if (q == nf) {
                    int dc = dstl[lo];
                    atomicAdd(&agg[((size_t)b * NC + dc) * 256 + w * 32 + nf * 16 + m15],
                              tv + bv * (float)(hi - lo));
                }
            }
        }
    }
}

// ------- node MLP (16-row tiles, MF=1, overlay) + fused tail blocks ----------
__global__ __launch_bounds__(256, 4) void node_tail_kernel(
    const float* __restrict__ h3, const float* __restrict__ agg,
    const float* __restrict__ nb0, const float* __restrict__ nb1, const float* __restrict__ nb2,
    const unsigned short* __restrict__ wpack, float* __restrict__ out,
    const float* __restrict__ la, const float* __restrict__ rb0,
    const float* __restrict__ rb1, const float* __restrict__ rb2,
    const float* __restrict__ rWs, const float* __restrict__ rbs,
    const int* __restrict__ lei) {
    __shared__ __align__(16) unsigned short S[32 * SH];   // covers 16*SA_N too

    const int tid = threadIdx.x, lane = tid & 63, w = tid >> 6;
    const int m15 = lane & 15, q = lane >> 4;

    if (blockIdx.x >= NODE_B) {   // ---------------- tail path ----------------
        const int blk = blockIdx.x - NODE_B;
        if (blk >= 185) {   // idx passthrough: float(latent_edge_index)
            for (int i = (blk - 185) * 256 + tid; i < OUT_IDX_N; i += 7 * 256)
                out[OUT_IDX_OFF + i] = (float)lei[i];
            return;
        }
        const int base = blk * 32;
        {   // stage [la(2)|zero(30)] at stride SH; 8 lanes per row, 16 pairs
            const int rr = tid >> 3, jj = tid & 7;
            unsigned short* Sr = S + rr * SH;
            unsigned v0 = 0;
            if (jj == 0 && base + rr < E_LAT) {
                float2 f = *(const float2*)(la + (size_t)(base + rr) * 2);
                v0 = packRTZ(f.x, f.y);
            }
            *(unsigned*)(Sr + 2 * jj) = v0;
            *(unsigned*)(Sr + 2 * (jj + 8)) = 0;
        }
        __syncthreads();

        f32x4 acc[2][4];
        zero_acc(acc);
        run_layer<2, 1>(S, SH, wpack + WOFF_R0, w * 4, m15, q, acc);   // K=32 (2 real)
        __syncthreads();
        epi_act(S, SH, acc, rb0, w * 64, 0, m15, q);
        __syncthreads();

        zero_acc(acc);
        run_layer<2, 8>(S, SH, wpack + WOFF_R1, w * 4, m15, q, acc);
        __syncthreads();
        epi_act(S, SH, acc, rb1, w * 64, 0, m15, q);
        __syncthreads();

        zero_acc(acc);
        run_layer<2, 8>(S, SH, wpack + WOFF_R2, w * 4, m15, q, acc);

        float* outA = out + OUT_ATTR_OFF;
#pragma unroll
        for (int nf = 0; nf < 4; ++nf) {
            int col = w * 64 + nf * 16 + m15;
            float bv = rb2[col] + rbs[col];
            float ws0 = rWs[col], ws1 = rWs[256 + col];
#pragma unroll
            for (int mf = 0; mf < 2; ++mf)
#pragma unroll
                for (int r4 = 0; r4 < 4; ++r4) {
                    int row = mf * 16 + q * 4 + r4;
                    int e = base + row;
                    if (e < E_LAT) {
                        float v = acc[mf][nf][r4] + bv + la[e * 2] * ws0 + la[e * 2 + 1] * ws1;
                        outA[(size_t)e * 256 + col] = v;
                    }
                }
        }
        return;
    }

    // ---------------- node path ----------------
    const int base = blockIdx.x * 16;

    // stage [h3(78)|agg(256)|zero(18)] at stride SA_N; 16 lanes per row
    {
        const int rr = tid >> 4, l16 = tid & 15;
        const int jj = base + rr;
        const int vl = jj < NROWS_NODE;
        const int c = vl ? jj % NC : 0;
        const float* hr = h3 + c * FIN;
        const float* ar = agg + (size_t)jj * 256;
        unsigned short* Sr = S + rr * SA_N;
#pragma unroll
        for (int tt = 0; tt < 12; ++tt) {
            int p = l16 + 16 * tt;
            if (p < 39) {
                float2 f = *(const float2*)(hr + 2 * p);
                *(unsigned*)(Sr + 2 * p) = packRTZ(f.x, f.y);
            } else if (p < 167) {
                unsigned v = 0;
                if (vl) { float2 f = *(const float2*)(ar + 2 * p - 78); v = packRTZ(f.x, f.y); }
                *(unsigned*)(Sr + 2 * p) = v;
            } else if (p < 176) {
                *(unsigned*)(Sr + 2 * p) = 0;   // cols 334..351 zero (read by K=352)
            }
        }
    }
    __syncthreads();

    f32x4 acc[1][4];
    zero_acc(acc);
    run_layer<1, 11>(S, SA_N, wpack + WOFF_N0, w * 4, m15, q, acc);   // K=352
    __syncthreads();
    epi_act(S, SA_N, acc, nb0, w * 64, 0, m15, q);
    __syncthreads();

    zero_acc(acc);
    run_layer<1, 8>(S, SA_N, wpack + WOFF_N1, w * 4, m15, q, acc);
    __syncthreads();
    epi_act(S, SA_N, acc, nb1, w * 64, 0, m15, q);
    __syncthreads();

    zero_acc(acc);
    run_layer<1, 8>(S, SA_N, wpack + WOFF_N2, w * 4, m15, q, acc);

#pragma unroll
    for (int nf = 0; nf < 4; ++nf) {
        int col = w * 64 + nf * 16 + m15;
        float bv = nb2[col];
#pragma unroll
        for (int r4 = 0; r4 < 4; ++r4) {
            int jj = base + q * 4 + r4;
            if (jj < NROWS_NODE) out[(size_t)jj * 256 + col] = acc[0][nf][r4] + bv;
        }
    }
}

// ---------------- launch ----------------
extern "C" void kernel_launch(void* const* d_in, const int* in_sizes, int n_in,
                              void* d_out, int out_size, void* d_ws, size_t ws_size,
                              hipStream_t stream) {
    const float* x      = (const float*)d_in[0];
    const int*   eidx   = (const int*)d_in[1];
    const float* eattr  = (const float*)d_in[2];
    const int*   lei    = (const int*)d_in[3];
    const float* la     = (const float*)d_in[4];
    const float* h3     = (const float*)d_in[5];
    const float* eW0 = (const float*)d_in[6],  *eb0 = (const float*)d_in[7];
    const float* eW1 = (const float*)d_in[8],  *eb1 = (const float*)d_in[9];
    const float* eW2 = (const float*)d_in[10], *eb2 = (const float*)d_in[11];
    const float* nW0 = (const float*)d_in[12], *nb0 = (const float*)d_in[13];
    const float* nW1 = (const float*)d_in[14], *nb1 = (const float*)d_in[15];
    const float* nW2 = (const float*)d_in[16], *nb2 = (const float*)d_in[17];
    const float* rW0 = (const float*)d_in[18], *rb0 = (const float*)d_in[19];
    const float* rW1 = (const float*)d_in[20], *rb1 = (const float*)d_in[21];
    const float* rW2 = (const float*)d_in[22], *rb2 = (const float*)d_in[23];
    const float* rWs = (const float*)d_in[24], *rbs = (const float*)d_in[25];

    char* ws = (char*)d_ws;
    float* agg    = (float*)(ws + AGG_OFF);
    int* cnt      = (int*)(ws + CNT_OFF);
    int* cur      = (int*)(ws + CUR_OFF);
    int* ssrc     = (int*)(ws + SSRC_OFF);
    short* sdst   = (short*)(ws + SDST_OFF);
    float2* sattr = (float2*)(ws + SATTR_OFF);
    unsigned short* wpack = (unsigned short*)(ws + WPACK_OFF);

    float* out = (float*)d_out;

    hipMemsetAsync(d_ws, 0, CUR_OFF, stream);   // agg + histogram counters

    pack_weights<<<1040, 512, 0, stream>>>(eW0, eW1, eW2, nW0, nW1, nW2, rW0, rW1, rW2, wpack);
    hist_kernel<<<254, 256, 0, stream>>>(eidx + E_EDGES, cnt);
    scan_kernel<<<1, 1024, 0, stream>>>(cnt, cur);
    scatter_kernel<<<254, 256, 0, stream>>>(eidx, eidx + E_EDGES, eattr, cur,
                                            ssrc, sdst, sattr);
    edge_mlp_kernel<<<EDGE_GRID, 512, 0, stream>>>(x, h3, eb0, eb1, eb2,
                                                   wpack, ssrc, sdst, sattr, agg);
    node_tail_kernel<<<NODE_B + TAIL_B, 256, 0, stream>>>(
        h3, agg, nb0, nb1, nb2, wpack, out,
        la, rb0, rb1, rb2, rWs, rbs, lei);
}

// Round 8
// 677.408 us; speedup vs baseline: 1.6342x; 1.6342x over previous
//
#include <hip/hip_runtime.h>

// ---------------- problem constants ----------------
#define E_EDGES 64800
#define NC      842
#define NB      8          // b*t = 2*4
#define FIN     78
#define E_LAT   5894
#define NROWS_NODE (NB*NC)   // 6736
#define NTILES_E 2025        // 64800/32 exact
#define NODE_B   421
#define TAIL_B   192         // tail blocks fused into node dispatch

// output layout (flat float32)
#define OUT_IDX_OFF   1724416
#define OUT_IDX_N     11788
#define OUT_ATTR_OFF  1736204

// workspace layout (bytes)
#define AGG_OFF    0
#define CNT_OFF    6897664
#define CUR_OFF    6901032
#define SSRC_OFF   6904400
#define SDST_OFF   7163600
#define SATTR_OFF  7293200
#define WPACK_OFF  7811600

// packed-weight element offsets (bf16 elements).  Edge L0 is now K=96:
// rows 0..77 = eW0[x-part], rows 78..79 = eW0[attr-part], rows 80..95 = 0.
// (h3-part of L0 is folded into the f32 bias table H3We = h3@eW0[78:156]+eb0.)
#define WOFF_E0 0
#define WOFF_E1 24576
#define WOFF_E2 90112
#define WOFF_N0 155648
#define WOFF_N1 245760
#define WOFF_N2 311296
#define WOFF_R0 376832
#define WOFF_R1 385024
#define WOFF_R2 450560

// LDS strides (bf16 elems): dword stride ≡ 3 or 5 (mod 8) keeps b128 A-frag
// reads ≤2-way bank-aliased (free).  262 -> 131 dw (3 mod 8); 362 -> 181 dw (5 mod 8).
#define SH   262
#define SA_N 362

typedef __bf16 bf16x8 __attribute__((ext_vector_type(8)));
typedef float  f32x4  __attribute__((ext_vector_type(4)));

__device__ __forceinline__ unsigned short f2bf(float f) {   // RNE (pack_weights only)
    unsigned u = __builtin_bit_cast(unsigned, f);
    return (unsigned short)((u + 0x7fffu + ((u >> 16) & 1u)) >> 16);
}
// RTZ pack of two floats into two bf16 in one v_perm_b32
__device__ __forceinline__ unsigned packRTZ(float lo, float hi) {
    return __builtin_amdgcn_perm(__builtin_bit_cast(unsigned, hi),
                                 __builtin_bit_cast(unsigned, lo), 0x07060302u);
}

template<int MF>
__device__ __forceinline__ void zero_acc(f32x4 (&acc)[MF][4]) {
#pragma unroll
    for (int mf = 0; mf < MF; ++mf)
#pragma unroll
        for (int nf = 0; nf < 4; ++nf)
            acc[mf][nf] = (f32x4){0.f, 0.f, 0.f, 0.f};
}

// C[MF*16 rows x 64-col wave slice] += A_lds * Wpacked, B-fragment prefetch.
template<int MF, int NKS>
__device__ __forceinline__ void run_layer(const unsigned short* lA, int strideA,
                                          const unsigned short* Wp, int nfg0,
                                          int m15, int q, f32x4 (&acc)[MF][4]) {
    const unsigned short* wp0 = Wp + (size_t)nfg0 * 512 + (threadIdx.x & 63) * 8;
    bf16x8 bcur[4], bnxt[4];
#pragma unroll
    for (int nf = 0; nf < 4; ++nf) bcur[nf] = *(const bf16x8*)(wp0 + nf * 512);
#pragma unroll
    for (int kk = 0; kk < NKS; ++kk) {
        if (kk + 1 < NKS) {
#pragma unroll
            for (int nf = 0; nf < 4; ++nf)
                bnxt[nf] = *(const bf16x8*)(wp0 + (size_t)(kk + 1) * 16 * 512 + nf * 512);
        }
        bf16x8 a[MF];
#pragma unroll
        for (int mf = 0; mf < MF; ++mf)
            a[mf] = *(const bf16x8*)(lA + (mf * 16 + m15) * strideA + kk * 32 + q * 8);
#pragma unroll
        for (int nf = 0; nf < 4; ++nf)
#pragma unroll
            for (int mf = 0; mf < MF; ++mf)
                acc[mf][nf] = __builtin_amdgcn_mfma_f32_16x16x32_bf16(a[mf], bcur[nf], acc[mf][nf], 0, 0, 0);
#pragma unroll
        for (int nf = 0; nf < 4; ++nf) bcur[nf] = bnxt[nf];
    }
}

// S[row*stride+col] = bf16_rtz(leaky(acc + bias[col])); leaky = max(y, 0.01y)
template<int MF>
__device__ __forceinline__ void epi_act(unsigned short* Sb, int stride, const f32x4 (&acc)[MF][4],
                                        const float* bias, int w, int m15, int q) {
#pragma unroll
    for (int nf = 0; nf < 4; ++nf) {
        int col = w * 64 + nf * 16 + m15;
        float bv = bias[col];
#pragma unroll
        for (int mf = 0; mf < MF; ++mf)
#pragma unroll
            for (int r4 = 0; r4 < 4; ++r4) {
                int row = mf * 16 + q * 4 + r4;
                float y = acc[mf][nf][r4] + bv;
                y = fmaxf(y, 0.01f * y);
                Sb[row * stride + col] = (unsigned short)(__builtin_bit_cast(unsigned, y) >> 16);
            }
    }
}

// ---------------- weight packing ----------------
__global__ void pack_weights(const float* s0, const float* s1, const float* s2,
                             const float* s3, const float* s4, const float* s5,
                             const float* s6, const float* s7, const float* s8,
                             unsigned short* wp) {
    const int ksA[9]  = {3, 8, 8, 11, 8, 8, 1, 8, 8};
    const int kaA[9]  = {96, 256, 256, 334, 256, 256, 2, 256, 256};
    const int offA[9] = {WOFF_E0, WOFF_E1, WOFF_E2, WOFF_N0, WOFF_N1, WOFF_N2,
                         WOFF_R0, WOFF_R1, WOFF_R2};
    const float* srcs[9] = {s0, s1, s2, s3, s4, s5, s6, s7, s8};
    int rem = blockIdx.x;
    int l = 0;
    while (rem >= ksA[l] * 16) { rem -= ksA[l] * 16; ++l; }
    int kk = rem >> 4, nf = rem & 15;
    int lane = threadIdx.x >> 3, j = threadIdx.x & 7;
    int k = kk * 32 + (lane >> 4) * 8 + j;
    int n = nf * 16 + (lane & 15);
    float v = 0.f;
    if (l == 0) {   // edge L0: [x(78)|attr(2)|zero(16)] row remap
        int sr = (k < 78) ? k : ((k < 80) ? 156 + (k - 78) : -1);
        if (sr >= 0) v = s0[sr * 256 + n];
    } else {
        v = (k < kaA[l]) ? srcs[l][k * 256 + n] : 0.f;
    }
    wp[(size_t)offA[l] + (size_t)(kk * 16 + nf) * 512 + lane * 8 + j] = f2bf(v);
}

// ---- H3We = h3 @ eW0[78:156] + eb0  (f32, 842x256) -> scratch in out-attr ----
__global__ __launch_bounds__(256) void h3mm_kernel(const float* __restrict__ h3,
                                                   const float* __restrict__ eW0,
                                                   const float* __restrict__ eb0,
                                                   float* __restrict__ h3we) {
    __shared__ float hs[16][80];
    const int tid = threadIdx.x;
    const int rbase = blockIdx.x * 16;
    for (int i = tid; i < 16 * 78; i += 256) {
        int r = i / 78, k = i % 78;
        int gr = rbase + r;
        hs[r][k] = (gr < NC) ? h3[gr * FIN + k] : 0.f;
    }
    __syncthreads();
    const int c = tid;
    float acc[16];
#pragma unroll
    for (int r = 0; r < 16; ++r) acc[r] = eb0[c];
    for (int k = 0; k < 78; ++k) {
        float wv = eW0[(78 + k) * 256 + c];
#pragma unroll
        for (int r = 0; r < 16; ++r) acc[r] = fmaf(hs[r][k], wv, acc[r]);
    }
#pragma unroll
    for (int r = 0; r < 16; ++r) {
        int gr = rbase + r;
        if (gr < NC) h3we[(size_t)gr * 256 + c] = acc[r];
    }
}

// ---------------- counting sort of edges by dst (+ gather sorted meta) ----------------
__global__ void hist_kernel(const int* __restrict__ dstA, int* __restrict__ cnt) {
    int e = blockIdx.x * 256 + threadIdx.x;
    if (e < E_EDGES) atomicAdd(&cnt[dstA[e]], 1);
}
__global__ void scan_kernel(const int* __restrict__ cnt, int* __restrict__ cursor) {
    __shared__ int s[1024];
    int t = threadIdx.x;
    s[t] = (t < NC) ? cnt[t] : 0;
    __syncthreads();
    for (int d = 1; d < 1024; d <<= 1) {
        int v = (t >= d) ? s[t - d] : 0;
        __syncthreads();
        s[t] += v;
        __syncthreads();
    }
    if (t < NC) cursor[t] = (t == 0) ? 0 : s[t - 1];
}
__global__ void scatter_kernel(const int* __restrict__ srcA, const int* __restrict__ dstA,
                               const float* __restrict__ eattr, int* __restrict__ cursor,
                               int* __restrict__ ssrc, short* __restrict__ sdst,
                               float2* __restrict__ sattr) {
    int e = blockIdx.x * 256 + threadIdx.x;
    if (e < E_EDGES) {
        int d = dstA[e];
        int p = atomicAdd(&cursor[d], 1);
        ssrc[p] = srcA[e];
        sdst[p] = (short)d;
        sattr[p] = ((const float2*)eattr)[e];
    }
}

// ------- fused 3-layer edge MLP: R0 schedule (32-row tiles, MF=2, 6/CU) ------
// L0 folded: A = [x(78)|attr(2)|pad16], K=96 (3 kk, was 5); h3-part of L0 is
// the f32 bias table H3We read in the L0 epilogue.  Staging drops the per-row
// h3 gather (39 float2 loads + 39 LDS write-pairs).
__global__ __launch_bounds__(256, 6) void edge_mlp_kernel(
    const float* __restrict__ x, const float* __restrict__ h3we,
    const float* __restrict__ eb1, const float* __restrict__ eb2,
    const unsigned short* __restrict__ wpack, const int* __restrict__ ssrc,
    const short* __restrict__ sdst, const float2* __restrict__ sattr,
    float* __restrict__ agg) {
    __shared__ __align__(16) unsigned short S[32 * SH];   // overlay: A(96) then H(256)
    __shared__ short dstl[32];
    __shared__ unsigned char starts[36];
    __shared__ int nseg;

    const int base = blockIdx.x * 32, b = blockIdx.y;
    const int tid = threadIdx.x, lane = tid & 63, w = tid >> 6;
    const int m15 = lane & 15, q = lane >> 4;

    if (tid < 32) dstl[tid] = sdst[base + tid];
    __syncthreads();

    if (tid == 0) {   // serial segment scan (32 rows), overlaps with staging
        int ns = 0; short prev = -2;
        for (int r = 0; r < 32; ++r) {
            short d = dstl[r];
            if (d != prev) { starts[ns++] = (unsigned char)r; prev = d; }
        }
        starts[ns] = 32;
        nseg = ns;
    }

    // stage layer-0 input [x(78)|attr(2)|zero(16)] at stride SH, RTZ pack.
    // 8 threads per row; grid is exact (64800 = 2025*32).  Cols 80..95 are
    // zeroed so first-layer garbage can never be NaN (weights there are 0).
    {
        const int rr = tid >> 3, j = tid & 7;
        const int eg = base + rr;
        const float* xr = x + ((size_t)b * E_EDGES + ssrc[eg]) * FIN;
        unsigned short* Sr = S + rr * SH;
#pragma unroll
        for (int t = 0; t < 6; ++t) {
            int p = j + 8 * t;
            if (p < 39) {
                float2 f = *(const float2*)(xr + 2 * p);
                *(unsigned*)(Sr + 2 * p) = packRTZ(f.x, f.y);
            } else if (p == 39) {
                float2 a2 = sattr[eg];
                *(unsigned*)(Sr + 78) = packRTZ(a2.x, a2.y);
            } else {   // p = 40..47 -> cols 80..95
                *(unsigned*)(Sr + 2 * p) = 0;
            }
        }
    }
    float bnf[4];
#pragma unroll
    for (int nf = 0; nf < 4; ++nf) bnf[nf] = eb2[w * 64 + nf * 16 + m15];
    __syncthreads();

    f32x4 acc[2][4];
    zero_acc<2>(acc);
    run_layer<2, 3>(S, SH, wpack + WOFF_E0, w * 4, m15, q, acc);   // K=96
    __syncthreads();
    // L0 epilogue: per-row f32 bias H3We[dst] (exact h3@W0 + eb0)
    {
#pragma unroll
        for (int mf = 0; mf < 2; ++mf)
#pragma unroll
            for (int r4 = 0; r4 < 4; ++r4) {
                int row = mf * 16 + q * 4 + r4;
                const float* hb = h3we + (size_t)dstl[row] * 256;
#pragma unroll
                for (int nf = 0; nf < 4; ++nf) {
                    int col = w * 64 + nf * 16 + m15;
                    float y = acc[mf][nf][r4] + hb[col];
                    y = fmaxf(y, 0.01f * y);
                    S[row * SH + col] = (unsigned short)(__builtin_bit_cast(unsigned, y) >> 16);
                }
            }
    }
    __syncthreads();

    zero_acc<2>(acc);
    run_layer<2, 8>(S, SH, wpack + WOFF_E1, w * 4, m15, q, acc);   // K=256
    __syncthreads();
    epi_act<2>(S, SH, acc, eb1, w, m15, q);
    __syncthreads();

    zero_acc<2>(acc);
    run_layer<2, 8>(S, SH, wpack + WOFF_E2, w * 4, m15, q, acc);

    // per-nf in-register segment reduce + predicated atomic flush
    const int ns = nseg;
#pragma unroll
    for (int nf = 0; nf < 4; ++nf) {
        for (int s = 0; s < ns; ++s) {
            const int lo = starts[s], hi = starts[s + 1];
            float t = 0.f;
#pragma unroll
            for (int mf = 0; mf < 2; ++mf)
#pragma unroll
                for (int r4 = 0; r4 < 4; ++r4) {
                    int row = mf * 16 + q * 4 + r4;
                    t += (row >= lo && row < hi) ? acc[mf][nf][r4] : 0.f;
                }
            t += __shfl_xor(t, 16, 64);
            t += __shfl_xor(t, 32, 64);
            if (q == nf) {
                int dc = dstl[lo];
                atomicAdd(&agg[((size_t)b * NC + dc) * 256 + w * 64 + nf * 16 + m15],
                          t + bnf[nf] * (float)(hi - lo));
            }
        }
    }
}

// ------- node MLP (16-row tiles, MF=1, overlay) + fused tail blocks ----------
__global__ __launch_bounds__(256, 4) void node_tail_kernel(
    const float* __restrict__ h3, const float* __restrict__ agg,
    const float* __restrict__ nb0, const float* __restrict__ nb1, const float* __restrict__ nb2,
    const unsigned short* __restrict__ wpack, float* __restrict__ out,
    const float* __restrict__ la, const float* __restrict__ rb0,
    const float* __restrict__ rb1, const float* __restrict__ rb2,
    const float* __restrict__ rWs, const float* __restrict__ rbs,
    const int* __restrict__ lei) {
    __shared__ __align__(16) unsigned short S[32 * SH];   // covers 16*SA_N too

    const int tid = threadIdx.x, lane = tid & 63, w = tid >> 6;
    const int m15 = lane & 15, q = lane >> 4;

    if (blockIdx.x >= NODE_B) {   // ---------------- tail path ----------------
        const int blk = blockIdx.x - NODE_B;
        if (blk >= 185) {   // idx passthrough: float(latent_edge_index)
            for (int i = (blk - 185) * 256 + tid; i < OUT_IDX_N; i += 7 * 256)
                out[OUT_IDX_OFF + i] = (float)lei[i];
            return;
        }
        const int base = blk * 32;
        {   // stage [la(2)|zero(30)] at stride SH; 8 lanes per row, 16 pairs
            const int rr = tid >> 3, jj = tid & 7;
            unsigned short* Sr = S + rr * SH;
            unsigned v0 = 0;
            if (jj == 0 && base + rr < E_LAT) {
                float2 f = *(const float2*)(la + (size_t)(base + rr) * 2);
                v0 = packRTZ(f.x, f.y);
            }
            *(unsigned*)(Sr + 2 * jj) = v0;
            *(unsigned*)(Sr + 2 * (jj + 8)) = 0;
        }
        __syncthreads();

        f32x4 acc[2][4];
        zero_acc<2>(acc);
        run_layer<2, 1>(S, SH, wpack + WOFF_R0, w * 4, m15, q, acc);   // K=32 (2 real)
        __syncthreads();
        epi_act<2>(S, SH, acc, rb0, w, m15, q);
        __syncthreads();

        zero_acc<2>(acc);
        run_layer<2, 8>(S, SH, wpack + WOFF_R1, w * 4, m15, q, acc);
        __syncthreads();
        epi_act<2>(S, SH, acc, rb1, w, m15, q);
        __syncthreads();

        zero_acc<2>(acc);
        run_layer<2, 8>(S, SH, wpack + WOFF_R2, w * 4, m15, q, acc);

        float* outA = out + OUT_ATTR_OFF;
#pragma unroll
        for (int nf = 0; nf < 4; ++nf) {
            int col = w * 64 + nf * 16 + m15;
            float bv = rb2[col] + rbs[col];
            float ws0 = rWs[col], ws1 = rWs[256 + col];
#pragma unroll
            for (int mf = 0; mf < 2; ++mf)
#pragma unroll
                for (int r4 = 0; r4 < 4; ++r4) {
                    int row = mf * 16 + q * 4 + r4;
                    int e = base + row;
                    if (e < E_LAT) {
                        float v = acc[mf][nf][r4] + bv + la[e * 2] * ws0 + la[e * 2 + 1] * ws1;
                        outA[(size_t)e * 256 + col] = v;
                    }
                }
        }
        return;
    }

    // ---------------- node path ----------------
    const int base = blockIdx.x * 16;

    // stage [h3(78)|agg(256)|zero(18)] at stride SA_N; 16 lanes per row
    {
        const int rr = tid >> 4, l16 = tid & 15;
        const int jj = base + rr;
        const int vl = jj < NROWS_NODE;
        const int c = vl ? jj % NC : 0;
        const float* hr = h3 + c * FIN;
        const float* ar = agg + (size_t)jj * 256;
        unsigned short* Sr = S + rr * SA_N;
#pragma unroll
        for (int tt = 0; tt < 12; ++tt) {
            int p = l16 + 16 * tt;
            if (p < 39) {
                float2 f = *(const float2*)(hr + 2 * p);
                *(unsigned*)(Sr + 2 * p) = packRTZ(f.x, f.y);
            } else if (p < 167) {
                unsigned v = 0;
                if (vl) { float2 f = *(const float2*)(ar + 2 * p - 78); v = packRTZ(f.x, f.y); }
                *(unsigned*)(Sr + 2 * p) = v;
            } else if (p < 176) {
                *(unsigned*)(Sr + 2 * p) = 0;   // cols 334..351 zero (read by K=352)
            }
        }
    }
    __syncthreads();

    f32x4 acc[1][4];
    zero_acc<1>(acc);
    run_layer<1, 11>(S, SA_N, wpack + WOFF_N0, w * 4, m15, q, acc);   // K=352
    __syncthreads();
    epi_act<1>(S, SA_N, acc, nb0, w, m15, q);
    __syncthreads();

    zero_acc<1>(acc);
    run_layer<1, 8>(S, SA_N, wpack + WOFF_N1, w * 4, m15, q, acc);
    __syncthreads();
    epi_act<1>(S, SA_N, acc, nb1, w, m15, q);
    __syncthreads();

    zero_acc<1>(acc);
    run_layer<1, 8>(S, SA_N, wpack + WOFF_N2, w * 4, m15, q, acc);

#pragma unroll
    for (int nf = 0; nf < 4; ++nf) {
        int col = w * 64 + nf * 16 + m15;
        float bv = nb2[col];
#pragma unroll
        for (int r4 = 0; r4 < 4; ++r4) {
            int jj = base + q * 4 + r4;
            if (jj < NROWS_NODE) out[(size_t)jj * 256 + col] = acc[0][nf][r4] + bv;
        }
    }
}

// ---------------- launch ----------------
extern "C" void kernel_launch(void* const* d_in, const int* in_sizes, int n_in,
                              void* d_out, int out_size, void* d_ws, size_t ws_size,
                              hipStream_t stream) {
    const float* x      = (const float*)d_in[0];
    const int*   eidx   = (const int*)d_in[1];
    const float* eattr  = (const float*)d_in[2];
    const int*   lei    = (const int*)d_in[3];
    const float* la     = (const float*)d_in[4];
    const float* h3     = (const float*)d_in[5];
    const float* eW0 = (const float*)d_in[6],  *eb0 = (const float*)d_in[7];
    const float* eW1 = (const float*)d_in[8],  *eb1 = (const float*)d_in[9];
    const float* eW2 = (const float*)d_in[10], *eb2 = (const float*)d_in[11];
    const float* nW0 = (const float*)d_in[12], *nb0 = (const float*)d_in[13];
    const float* nW1 = (const float*)d_in[14], *nb1 = (const float*)d_in[15];
    const float* nW2 = (const float*)d_in[16], *nb2 = (const float*)d_in[17];
    const float* rW0 = (const float*)d_in[18], *rb0 = (const float*)d_in[19];
    const float* rW1 = (const float*)d_in[20], *rb1 = (const float*)d_in[21];
    const float* rW2 = (const float*)d_in[22], *rb2 = (const float*)d_in[23];
    const float* rWs = (const float*)d_in[24], *rbs = (const float*)d_in[25];

    char* ws = (char*)d_ws;
    float* agg    = (float*)(ws + AGG_OFF);
    int* cnt      = (int*)(ws + CNT_OFF);
    int* cur      = (int*)(ws + CUR_OFF);
    int* ssrc     = (int*)(ws + SSRC_OFF);
    short* sdst   = (short*)(ws + SDST_OFF);
    float2* sattr = (float2*)(ws + SATTR_OFF);
    unsigned short* wpack = (unsigned short*)(ws + WPACK_OFF);

    float* out = (float*)d_out;
    // H3We scratch lives in the out-attr region: written by h3mm, read by the
    // edge kernel, then overwritten with the real attrs by node_tail (serial).
    float* h3we = out + OUT_ATTR_OFF;

    hipMemsetAsync(d_ws, 0, CUR_OFF, stream);   // agg + histogram counters

    pack_weights<<<1008, 512, 0, stream>>>(eW0, eW1, eW2, nW0, nW1, nW2, rW0, rW1, rW2, wpack);
    h3mm_kernel<<<53, 256, 0, stream>>>(h3, eW0, eb0, h3we);
    hist_kernel<<<254, 256, 0, stream>>>(eidx + E_EDGES, cnt);
    scan_kernel<<<1, 1024, 0, stream>>>(cnt, cur);
    scatter_kernel<<<254, 256, 0, stream>>>(eidx, eidx + E_EDGES, eattr, cur,
                                            ssrc, sdst, sattr);
    edge_mlp_kernel<<<dim3(NTILES_E, NB), 256, 0, stream>>>(x, h3we, eb1, eb2,
                                                            wpack, ssrc, sdst, sattr, agg);
    node_tail_kernel<<<NODE_B + TAIL_B, 256, 0, stream>>>(
        h3, agg, nb0, nb1, nb2, wpack, out,
        la, rb0, rb1, rb2, rWs, rbs, lei);
}